// Round 8
// baseline (148.420 us; speedup 1.0000x reference)
//
#include <hip/hip_runtime.h>
#include <hip/hip_bf16.h>
#include <math.h>

#define DIM 512
#define NH 8
#define HD 64
#define TT 1024
#define CH 32      // chunks per (b,h) sequence
#define CL 32      // chunk length (CH*CL == TT)
#define EPSF 1e-5f
#define LN2F 0.69314718056f
#define LOG2EF 1.44269504089f

typedef unsigned short ushort_t;
typedef __attribute__((ext_vector_type(8))) short bf16x8;
typedef __attribute__((ext_vector_type(4))) float f32x4;

// raw gfx950 hardware transcendentals: v_exp_f32 = 2^x, v_log_f32 = log2(x)
__device__ __forceinline__ float fexp2(float x) { return __builtin_amdgcn_exp2f(x); }
__device__ __forceinline__ float flog2(float x) { return __builtin_amdgcn_logf(x); }

__device__ __forceinline__ ushort_t f2bf(float f) {
    union { float f; unsigned u; } v; v.f = f;
    unsigned r = v.u + 0x7FFFu + ((v.u >> 16) & 1u);
    return (ushort_t)(r >> 16);
}
__device__ __forceinline__ float bf2f(ushort_t h) {
    union { unsigned u; float f; } v; v.u = ((unsigned)h) << 16;
    return v.f;
}

// ---------------- cvt: x -> bf16 hi/lo ----------------
__launch_bounds__(256)
__global__ void k_cvt_x(const float* __restrict__ x, ushort_t* __restrict__ xh,
                        ushort_t* __restrict__ xl)
{
    int i = (blockIdx.x * 256 + threadIdx.x) * 4;
    float4 v = *(const float4*)&x[i];
    ushort4 h, l;
    h.x = f2bf(v.x); l.x = f2bf(v.x - bf2f(h.x));
    h.y = f2bf(v.y); l.y = f2bf(v.y - bf2f(h.y));
    h.z = f2bf(v.z); l.z = f2bf(v.z - bf2f(h.z));
    h.w = f2bf(v.w); l.w = f2bf(v.w - bf2f(h.w));
    *(ushort4*)&xh[i] = h;
    *(ushort4*)&xl[i] = l;
}

// ---------------- cvt: weights -> transposed bf16 [n][k] ----------------
__launch_bounds__(256)
__global__ void k_cvt_w(const float* __restrict__ wq, const float* __restrict__ wk,
                        const float* __restrict__ wv, const float* __restrict__ wo,
                        ushort_t* __restrict__ wTh, ushort_t* __restrict__ wTl,
                        ushort_t* __restrict__ wTo)
{
    const int mat = blockIdx.z;
    const float* w = (mat == 0) ? wq : (mat == 1) ? wk : (mat == 2) ? wv : wo;
    const int n  = blockIdx.x * 64 + (threadIdx.x & 63);
    const int k0 = blockIdx.y * 128 + (threadIdx.x >> 6) * 32;

    ushort_t hb[32], lb[32];
#pragma unroll
    for (int j = 0; j < 32; j++) {
        float v = w[(size_t)(k0 + j) * DIM + n];
        hb[j] = f2bf(v);
        lb[j] = f2bf(v - bf2f(hb[j]));
    }
    if (mat < 3) {
        ushort_t* dh = wTh + (size_t)mat * DIM * DIM + (size_t)n * DIM + k0;
        ushort_t* dl = wTl + (size_t)mat * DIM * DIM + (size_t)n * DIM + k0;
#pragma unroll
        for (int j = 0; j < 8; j++) {
            ushort4 th = { hb[4*j], hb[4*j+1], hb[4*j+2], hb[4*j+3] };
            ushort4 tl = { lb[4*j], lb[4*j+1], lb[4*j+2], lb[4*j+3] };
            *(ushort4*)&dh[4*j] = th;
            *(ushort4*)&dl[4*j] = tl;
        }
    } else {
        ushort_t* dh = wTo + (size_t)n * DIM + k0;
#pragma unroll
        for (int j = 0; j < 8; j++) {
            ushort4 th = { hb[4*j], hb[4*j+1], hb[4*j+2], hb[4*j+3] };
            *(ushort4*)&dh[4*j] = th;
        }
    }
}

// ---------------- Kernel 1: QKV projection via MFMA, reg-double-buffered ------
// grid (NH, rows/64, 3), 256 thr (4 waves). Wave: 16 rows x 64 cols.
// __launch_bounds__(256,3): grid gives exactly 3 blocks/CU (3 waves/EU), so
// declare it -> VGPR cap ~170 -> the 2-deep register pipeline stays live.
__launch_bounds__(256, 3)
__global__ void k_gemm_qkv(const ushort_t* __restrict__ xh, const ushort_t* __restrict__ xl,
                           const ushort_t* __restrict__ wTh, const ushort_t* __restrict__ wTl,
                           const float* __restrict__ bq, const float* __restrict__ bk,
                           const float* __restrict__ bv,
                           const float* __restrict__ lbeta, const float* __restrict__ ltemp,
                           float* __restrict__ Qf2, float* __restrict__ Kf,
                           float* __restrict__ Vv2)
{
    const int z = blockIdx.z, h = blockIdx.x;
    const int rowBase = blockIdx.y * 64;
    const float* bias = (z == 0) ? bq : (z == 1) ? bk : bv;

    const int tid = threadIdx.x;
    const int w16 = (tid >> 6) * 16;
    const int l = tid & 63;
    const int m = l & 15, g = l >> 4;

    const int arow = rowBase + w16 + m;
    const ushort_t* axh = xh + (size_t)arow * DIM + g * 8;
    const ushort_t* axl = xl + (size_t)arow * DIM + g * 8;
    const ushort_t* bwh = wTh + (size_t)z * DIM * DIM + (size_t)(h * 64 + m) * DIM + g * 8;
    const ushort_t* bwl = wTl + (size_t)z * DIM * DIM + (size_t)(h * 64 + m) * DIM + g * 8;

    f32x4 acc[4] = { {0,0,0,0}, {0,0,0,0}, {0,0,0,0}, {0,0,0,0} };

    bf16x8 Ah0, Al0, Bh0[4], Bl0[4];
    bf16x8 Ah1, Al1, Bh1[4], Bl1[4];

#define LOADF(AH, AL, BH, BL, K) { \
    AH = *(const bf16x8*)(axh + (K)); AL = *(const bf16x8*)(axl + (K)); \
    BH[0] = *(const bf16x8*)(bwh + 0 * 16 * DIM + (K)); \
    BH[1] = *(const bf16x8*)(bwh + 1 * 16 * DIM + (K)); \
    BH[2] = *(const bf16x8*)(bwh + 2 * 16 * DIM + (K)); \
    BH[3] = *(const bf16x8*)(bwh + 3 * 16 * DIM + (K)); \
    BL[0] = *(const bf16x8*)(bwl + 0 * 16 * DIM + (K)); \
    BL[1] = *(const bf16x8*)(bwl + 1 * 16 * DIM + (K)); \
    BL[2] = *(const bf16x8*)(bwl + 2 * 16 * DIM + (K)); \
    BL[3] = *(const bf16x8*)(bwl + 3 * 16 * DIM + (K)); }

#define MFMA3(AH, AL, BH, BL) { \
    _Pragma("unroll") \
    for (int n = 0; n < 4; n++) { \
        acc[n] = __builtin_amdgcn_mfma_f32_16x16x32_bf16(AH, BH[n], acc[n], 0, 0, 0); \
        acc[n] = __builtin_amdgcn_mfma_f32_16x16x32_bf16(AL, BH[n], acc[n], 0, 0, 0); \
        acc[n] = __builtin_amdgcn_mfma_f32_16x16x32_bf16(AH, BL[n], acc[n], 0, 0, 0); \
    } }

    LOADF(Ah0, Al0, Bh0, Bl0, 0)
#pragma unroll
    for (int k0 = 0; k0 < DIM; k0 += 64) {
        LOADF(Ah1, Al1, Bh1, Bl1, k0 + 32)
        MFMA3(Ah0, Al0, Bh0, Bl0)
        if (k0 + 64 < DIM) { LOADF(Ah0, Al0, Bh0, Bl0, k0 + 64) }
        MFMA3(Ah1, Al1, Bh1, Bl1)
    }
#undef LOADF
#undef MFMA3

    // epilogue: C/D layout col=lane&15, row=(lane>>4)*4+reg  [m89 verified]
    if (z == 2) {
#pragma unroll
        for (int n = 0; n < 4; n++) {
            int c = n * 16 + m;
            float bval = bias[h * 64 + c];
#pragma unroll
            for (int r = 0; r < 4; r++) {
                int rr = rowBase + w16 + g * 4 + r;
                int bb = rr >> 10, t = rr & (TT - 1);
                Vv2[(((size_t)(bb * NH + h)) * TT + t) * HD + c] = (acc[n][r] + bval) * LOG2EF;
            }
        }
    } else {
        float beta = expf(lbeta[h]);
        float itemp = 1.0f / expf(ltemp[h]);
        float oscale = (z == 0) ? (LN2F / beta) : (1.0f / beta);
        float* __restrict__ dst = (z == 0) ? Qf2 : Kf;
#pragma unroll
        for (int n = 0; n < 4; n++) {
            int c = n * 16 + m;
            float bval = bias[h * 64 + c];
#pragma unroll
            for (int r = 0; r < 4; r++) {
                int rr = rowBase + w16 + g * 4 + r;
                int bb = rr >> 10, t = rr & (TT - 1);
                float val = (acc[n][r] + bval) * itemp;
                float zz = beta * val;
                float sp = (fmaxf(zz, 0.f) + log1pf(expf(-fabsf(zz)))) * oscale;
                dst[(((size_t)(bb * NH + h)) * TT + t) * HD + c] = sp;
            }
        }
    }
}

// ---------------- Kernel 2: per-chunk local sums ----------------
__launch_bounds__(256)
__global__ void k_chunk_reduce(const float* __restrict__ Kf, const float* __restrict__ Vv2,
                               float* __restrict__ aA, float* __restrict__ aD,
                               float* __restrict__ aCM)
{
    const int c = blockIdx.x >> 1, qh = blockIdx.x & 1;
    const int bh = blockIdx.z * NH + blockIdx.y;
    const int tid = threadIdx.x;

    __shared__ __align__(16) float sK[CL * HD];
    __shared__ __align__(16) float sV2[CL * HD];
    __shared__ __align__(16) float sM02[CL * HD];

    size_t base = ((size_t)bh * TT + (size_t)c * CL) * HD;
    const float4* K4 = (const float4*)(Kf + base);
    const float4* V4 = (const float4*)(Vv2 + base);
#pragma unroll
    for (int r = 0; r < 2; r++) {
        int f = tid + 256 * r;
        float4 kv = K4[f];
        ((float4*)sK)[f] = kv;
        float4 mm;
        mm.x = flog2(kv.x + EPSF); mm.y = flog2(kv.y + EPSF);
        mm.z = flog2(kv.z + EPSF); mm.w = flog2(kv.w + EPSF);
        ((float4*)sM02)[f] = mm;
        ((float4*)sV2)[f] = V4[f];
    }
    __syncthreads();

    const int p = tid & 63, qo = tid >> 6;
    const int q0 = qh * 32 + qo * 8;
    float A[8] = {};
    float AD = 0.f, cmx = 0.f;
    const bool doD = (qh == 0) && (tid < 64);

    for (int s = 0; s < CL; s++) {
        float vp = sV2[s * HD + p];
        float mp = sM02[s * HD + p];
        float4 ka = *(const float4*)&sK[s * HD + q0];
        float4 kb = *(const float4*)&sK[s * HD + q0 + 4];
        A[0] += fexp2(fmaf(vp, ka.x, mp));
        A[1] += fexp2(fmaf(vp, ka.y, mp));
        A[2] += fexp2(fmaf(vp, ka.z, mp));
        A[3] += fexp2(fmaf(vp, ka.w, mp));
        A[4] += fexp2(fmaf(vp, kb.x, mp));
        A[5] += fexp2(fmaf(vp, kb.y, mp));
        A[6] += fexp2(fmaf(vp, kb.z, mp));
        A[7] += fexp2(fmaf(vp, kb.w, mp));
        if (doD) {
            float kn = sK[s * HD + tid];
            float mn = sM02[s * HD + tid];
            AD += fexp2(fmaf(kn, LOG2EF, mn));
            cmx = fmaxf(cmx, kn + EPSF);
        }
    }

    size_t abase = ((size_t)bh * CH + c) * 4096 + (size_t)p * HD + q0;
    float4 o0 = { A[0], A[1], A[2], A[3] };
    float4 o1 = { A[4], A[5], A[6], A[7] };
    *(float4*)&aA[abase] = o0;
    *(float4*)&aA[abase + 4] = o1;
    if (doD) {
        size_t dbase = ((size_t)bh * CH + c) * HD + tid;
        aD[dbase] = AD; aCM[dbase] = cmx;
    }
}

// ---------------- Kernel 3: exclusive scan of chunk aggregates ----------------
__global__ void k_scan_agg(float* __restrict__ aA, float* __restrict__ aD,
                           float* __restrict__ aCM, int BH)
{
    int idx = blockIdx.x * 256 + threadIdx.x;
    int nA = BH * 4096, nD = BH * 64;
    if (idx < nA) {
        int bh = idx >> 12, pn = idx & 4095;
        float Sr = 0.f;
        for (int c = 0; c < CH; c++) {
            size_t off = ((size_t)bh * CH + c) * 4096 + pn;
            float t = aA[off]; aA[off] = Sr; Sr += t;
        }
    } else if (idx < nA + nD) {
        int i = idx - nA; int bh = i >> 6, n = i & 63;
        float Sr = 0.f;
        for (int c = 0; c < CH; c++) {
            size_t off = ((size_t)bh * CH + c) * HD + n;
            float t = aD[off]; aD[off] = Sr; Sr += t;
        }
    } else if (idx < nA + 2 * nD) {
        int i = idx - nA - nD; int bh = i >> 6, n = i & 63;
        float r = 0.f;
        for (int c = 0; c < CH; c++) {
            size_t off = ((size_t)bh * CH + c) * HD + n;
            float v = aCM[off]; aCM[off] = r; r = fmaxf(r, v);
        }
    }
}

// ---------------- Kernel 4: denominator / c1 per t ----------------
__launch_bounds__(64)
__global__ void k_den(const float* __restrict__ Kf, const float* __restrict__ Qf2,
                      const float* __restrict__ aD, const float* __restrict__ aCM,
                      float* __restrict__ c1f, float* __restrict__ invd)
{
    const int c = blockIdx.x;
    const int bh = blockIdx.z * NH + blockIdx.y;
    const int n = threadIdx.x;
    size_t dbase = ((size_t)bh * CH + c) * HD + n;
    float AD = aD[dbase], cmx = aCM[dbase];
    size_t base = ((size_t)bh * TT + (size_t)c * CL) * HD + n;
    float* outc = c1f + (size_t)bh * TT + c * CL;
    float* outi = invd + (size_t)bh * TT + c * CL;

    for (int s = 0; s < CL; s++) {
        float kn = Kf[base + (size_t)s * HD];
        float qn = Qf2[base + (size_t)s * HD];
        float mn = flog2(kn + EPSF);
        AD += fexp2(fmaf(kn, LOG2EF, mn));
        cmx = fmaxf(cmx, kn + EPSF);
        float t1 = qn * flog2(cmx);
        float t2 = qn * flog2(AD);
#pragma unroll
        for (int off = 1; off <= 32; off <<= 1) {
            t1 += __shfl_xor(t1, off);
            t2 += __shfl_xor(t2, off);
        }
        if (n == 0) {
            outc[s] = t1;
            outi[s] = 1.0f / (t2 - t1 + EPSF);
        }
    }
}

// ---------------- Kernel 5: within-chunk rescan + output Y (bf16) -------------
__launch_bounds__(256)
__global__ void k_chunk_out(const float* __restrict__ Kf, const float* __restrict__ Vv2,
                            const float* __restrict__ Qf2, const float* __restrict__ aA,
                            const float* __restrict__ c1f, const float* __restrict__ invd,
                            const float* __restrict__ lsharp, ushort_t* __restrict__ Ymb)
{
    const int c = blockIdx.x, hh = blockIdx.y, bb = blockIdx.z;
    const int bh = bb * NH + hh;
    const int tid = threadIdx.x;

    __shared__ __align__(16) float sK[CL * HD];
    __shared__ __align__(16) float sV2[CL * HD];
    __shared__ __align__(16) float sM02[CL * HD];
    __shared__ __align__(16) float sQ2[CL * HD];

    size_t base = ((size_t)bh * TT + (size_t)c * CL) * HD;
    const float4* K4 = (const float4*)(Kf + base);
    const float4* V4 = (const float4*)(Vv2 + base);
    const float4* Q4 = (const float4*)(Qf2 + base);
#pragma unroll
    for (int r = 0; r < 2; r++) {
        int f = tid + 256 * r;
        float4 kv = K4[f];
        ((float4*)sK)[f] = kv;
        float4 mm;
        mm.x = flog2(kv.x + EPSF); mm.y = flog2(kv.y + EPSF);
        mm.z = flog2(kv.z + EPSF); mm.w = flog2(kv.w + EPSF);
        ((float4*)sM02)[f] = mm;
        ((float4*)sV2)[f] = V4[f];
        ((float4*)sQ2)[f] = Q4[f];
    }
    __syncthreads();

    const int lane = tid & 63, w = tid >> 6;
    const int g = lane >> 3, qil = lane & 7;
    const int qA = w * 8 + qil, qB = qA + 32;
    const int p0 = g * 8;

    float A[8], Bq[8];
    size_t abase = ((size_t)bh * CH + c) * 4096;
#pragma unroll
    for (int j = 0; j < 8; j++) {
        A[j]  = aA[abase + (size_t)(p0 + j) * HD + qA];
        Bq[j] = aA[abase + (size_t)(p0 + j) * HD + qB];
    }
    const float sharp = expf(lsharp[hh]);
    const float invT = 1.0f / (float)TT;
    const float* c1p = c1f + (size_t)bh * TT + c * CL;
    const float* ivp = invd + (size_t)bh * TT + c * CL;

    for (int s = 0; s < CL; s++) {
        float kqA = sK[s * HD + qA];
        float kqB = sK[s * HD + qB];
        float partA = 0.f, partB = 0.f;
#pragma unroll
        for (int j4 = 0; j4 < 2; j4++) {
            float4 vv = *(const float4*)&sV2[s * HD + p0 + j4 * 4];
            float4 mm = *(const float4*)&sM02[s * HD + p0 + j4 * 4];
            float4 qv = *(const float4*)&sQ2[s * HD + p0 + j4 * 4];
#define STEP(comp, jj) { \
            A[jj]  += fexp2(fmaf(vv.comp, kqA, mm.comp)); \
            partA = fmaf(qv.comp, flog2(A[jj]), partA); \
            Bq[jj] += fexp2(fmaf(vv.comp, kqB, mm.comp)); \
            partB = fmaf(qv.comp, flog2(Bq[jj]), partB); }
            STEP(x, j4 * 4 + 0)
            STEP(y, j4 * 4 + 1)
            STEP(z, j4 * 4 + 2)
            STEP(w, j4 * 4 + 3)
#undef STEP
        }
        partA += __shfl_xor(partA, 8);
        partA += __shfl_xor(partA, 16);
        partA += __shfl_xor(partA, 32);
        partB += __shfl_xor(partB, 8);
        partB += __shfl_xor(partB, 16);
        partB += __shfl_xor(partB, 32);

        float c1v = c1p[s], iv = ivp[s];
        int tg = c * CL + s;
        float scale = (float)(tg + 1) * invT;
        float yA = (partA - c1v) * iv;
        float yB = (partB - c1v) * iv;
        float oA = copysignf(fexp2(sharp * flog2(fabsf(yA))), yA) * scale;
        float oB = copysignf(fexp2(sharp * flog2(fabsf(yB))), yB) * scale;
        if (g == 0) {
            ushort_t* yrow = Ymb + ((size_t)(bb * TT + tg)) * DIM + hh * HD;
            yrow[qA] = f2bf(oA);
            yrow[qB] = f2bf(oB);
        }
    }
}

// ---------------- Kernel 6: output projection via MFMA ----------------
// 32x64 block tile, 4 waves (2 row-groups x 2 col-groups), grid 512 = 2/CU.
// __launch_bounds__(256,2): 2 waves/EU -> VGPR cap 256, full load hoisting.
__launch_bounds__(256, 2)
__global__ void k_gemm_out(const ushort_t* __restrict__ Ymb, const ushort_t* __restrict__ wTo,
                           const float* __restrict__ bias, float* __restrict__ out)
{
    const int colBase = blockIdx.x * 64;
    const int rowBase = blockIdx.y * 32;

    const int tid = threadIdx.x;
    const int wv = tid >> 6;
    const int rowOff = (wv & 1) * 16;
    const int colOff = (wv >> 1) * 32;
    const int l = tid & 63;
    const int m = l & 15, g = l >> 4;

    const ushort_t* ax = Ymb + (size_t)(rowBase + rowOff + m) * DIM + g * 8;
    const ushort_t* bw = wTo + (size_t)(colBase + colOff + m) * DIM + g * 8;

    f32x4 acc[2] = { {0,0,0,0}, {0,0,0,0} };

    bf16x8 A0, B0[2], A1, B1[2];
#define LOADF(AV, BV, K) { \
    AV = *(const bf16x8*)(ax + (K)); \
    BV[0] = *(const bf16x8*)(bw + 0 * 16 * DIM + (K)); \
    BV[1] = *(const bf16x8*)(bw + 1 * 16 * DIM + (K)); }
#define MFMA1(AV, BV) { \
    acc[0] = __builtin_amdgcn_mfma_f32_16x16x32_bf16(AV, BV[0], acc[0], 0, 0, 0); \
    acc[1] = __builtin_amdgcn_mfma_f32_16x16x32_bf16(AV, BV[1], acc[1], 0, 0, 0); }

    LOADF(A0, B0, 0)
#pragma unroll
    for (int k0 = 0; k0 < DIM; k0 += 64) {
        LOADF(A1, B1, k0 + 32)
        MFMA1(A0, B0)
        if (k0 + 64 < DIM) { LOADF(A0, B0, k0 + 64) }
        MFMA1(A1, B1)
    }
#undef LOADF
#undef MFMA1

#pragma unroll
    for (int n = 0; n < 2; n++) {
        int c = colBase + colOff + n * 16 + m;
        float bval = bias[c];
#pragma unroll
        for (int r = 0; r < 4; r++) {
            int rr = rowBase + rowOff + g * 4 + r;
            out[(size_t)rr * DIM + c] = acc[n][r] + bval;
        }
    }
}

extern "C" void kernel_launch(void* const* d_in, const int* in_sizes, int n_in,
                              void* d_out, int out_size, void* d_ws, size_t ws_size,
                              hipStream_t stream)
{
    const float* x  = (const float*)d_in[0];
    const float* wq = (const float*)d_in[1];
    const float* bq = (const float*)d_in[2];
    const float* wk = (const float*)d_in[3];
    const float* bk = (const float*)d_in[4];
    const float* wv = (const float*)d_in[5];
    const float* bv = (const float*)d_in[6];
    const float* wo = (const float*)d_in[7];
    const float* bo = (const float*)d_in[8];
    const float* lb = (const float*)d_in[9];
    const float* lt = (const float*)d_in[10];
    const float* ls = (const float*)d_in[11];

    const int B  = in_sizes[0] / (TT * DIM);   // 2
    const int BH = B * NH;                     // 16

    float* ws = (float*)d_ws;
    const size_t nQ = (size_t)BH * TT * HD;      // 1,048,576 floats
    float* Qf2 = ws;
    float* Kf  = Qf2 + nQ;
    float* Vv2 = Kf + nQ;
    float* region = Vv2 + nQ;                    // phase-aliased region

    // phase 1-2 (cvt + qkv): bf16 staging lives in region
    ushort_t* xh  = (ushort_t*)region;                                  // B*TT*DIM bf16
    ushort_t* xl  = xh + (size_t)B * TT * DIM;
    ushort_t* wTh = (ushort_t*)(region + (size_t)B * TT * DIM);         // 3*DIM*DIM bf16
    ushort_t* wTl = wTh + (size_t)3 * DIM * DIM;
    // phase 3+ : scan state overwrites the staging area
    ushort_t* Ymb = (ushort_t*)region;                                  // B*TT*DIM bf16
    float* aA  = region + (size_t)B * TT * DIM;                         // BH*CH*4096
    float* aD  = aA  + (size_t)BH * CH * 4096;
    float* aCM = aD  + (size_t)BH * CH * HD;
    float* c1f = aCM + (size_t)BH * CH * HD;
    float* invd= c1f + (size_t)BH * TT;
    ushort_t* wTo = (ushort_t*)(invd + (size_t)BH * TT);                // persists to end

    k_cvt_x<<<(B * TT * DIM) / 1024, 256, 0, stream>>>(x, xh, xl);

    dim3 gw(DIM / 64, DIM / 128, 4);
    k_cvt_w<<<gw, 256, 0, stream>>>(wq, wk, wv, wo, wTh, wTl, wTo);

    dim3 g1(NH, (B * TT) / 64, 3);
    k_gemm_qkv<<<g1, 256, 0, stream>>>(xh, xl, wTh, wTl, bq, bk, bv, lb, lt, Qf2, Kf, Vv2);

    dim3 g2(CH * 2, NH, B);
    k_chunk_reduce<<<g2, 256, 0, stream>>>(Kf, Vv2, aA, aD, aCM);

    int ntot = BH * 4096 + 2 * BH * 64;
    k_scan_agg<<<(ntot + 255) / 256, 256, 0, stream>>>(aA, aD, aCM, BH);

    dim3 g4(CH, NH, B);
    k_den<<<g4, 64, 0, stream>>>(Kf, Qf2, aD, aCM, c1f, invd);

    k_chunk_out<<<g4, 256, 0, stream>>>(Kf, Vv2, Qf2, aA, c1f, invd, ls, Ymb);

    dim3 g6(DIM / 64, (B * TT) / 32);
    k_gemm_out<<<g6, 256, 0, stream>>>(Ymb, wTo, bo, (float*)d_out);
}

// Round 9
// 105.779 us; speedup vs baseline: 1.4031x; 1.4031x over previous
//
#include <hip/hip_runtime.h>
#include <hip/hip_bf16.h>
#include <math.h>

#define DIM 512
#define NH 8
#define HD 64
#define TT 1024
#define CH 32      // chunks per (b,h) sequence
#define CL 32      // chunk length (CH*CL == TT)
#define EPSF 1e-5f
#define LN2F 0.69314718056f
#define LOG2EF 1.44269504089f

typedef unsigned short ushort_t;
typedef __attribute__((ext_vector_type(8))) short bf16x8;
typedef __attribute__((ext_vector_type(4))) float f32x4;

// raw gfx950 hardware transcendentals: v_exp_f32 = 2^x, v_log_f32 = log2(x)
__device__ __forceinline__ float fexp2(float x) { return __builtin_amdgcn_exp2f(x); }
__device__ __forceinline__ float flog2(float x) { return __builtin_amdgcn_logf(x); }

__device__ __forceinline__ ushort_t f2bf(float f) {
    union { float f; unsigned u; } v; v.f = f;
    unsigned r = v.u + 0x7FFFu + ((v.u >> 16) & 1u);
    return (ushort_t)(r >> 16);
}
__device__ __forceinline__ float bf2f(ushort_t h) {
    union { unsigned u; float f; } v; v.u = ((unsigned)h) << 16;
    return v.f;
}

// ---------------- cvt: x -> bf16 hi/lo ----------------
__launch_bounds__(256)
__global__ void k_cvt_x(const float* __restrict__ x, ushort_t* __restrict__ xh,
                        ushort_t* __restrict__ xl)
{
    int i = (blockIdx.x * 256 + threadIdx.x) * 4;
    float4 v = *(const float4*)&x[i];
    ushort4 h, l;
    h.x = f2bf(v.x); l.x = f2bf(v.x - bf2f(h.x));
    h.y = f2bf(v.y); l.y = f2bf(v.y - bf2f(h.y));
    h.z = f2bf(v.z); l.z = f2bf(v.z - bf2f(h.z));
    h.w = f2bf(v.w); l.w = f2bf(v.w - bf2f(h.w));
    *(ushort4*)&xh[i] = h;
    *(ushort4*)&xl[i] = l;
}

// ---------------- cvt: weights -> transposed bf16 [n][k] ----------------
__launch_bounds__(256)
__global__ void k_cvt_w(const float* __restrict__ wq, const float* __restrict__ wk,
                        const float* __restrict__ wv, const float* __restrict__ wo,
                        ushort_t* __restrict__ wTh, ushort_t* __restrict__ wTl,
                        ushort_t* __restrict__ wTo)
{
    const int mat = blockIdx.z;
    const float* w = (mat == 0) ? wq : (mat == 1) ? wk : (mat == 2) ? wv : wo;
    const int n  = blockIdx.x * 64 + (threadIdx.x & 63);
    const int k0 = blockIdx.y * 128 + (threadIdx.x >> 6) * 32;

    ushort_t hb[32], lb[32];
#pragma unroll
    for (int j = 0; j < 32; j++) {
        float v = w[(size_t)(k0 + j) * DIM + n];
        hb[j] = f2bf(v);
        lb[j] = f2bf(v - bf2f(hb[j]));
    }
    if (mat < 3) {
        ushort_t* dh = wTh + (size_t)mat * DIM * DIM + (size_t)n * DIM + k0;
        ushort_t* dl = wTl + (size_t)mat * DIM * DIM + (size_t)n * DIM + k0;
#pragma unroll
        for (int j = 0; j < 8; j++) {
            ushort4 th = { hb[4*j], hb[4*j+1], hb[4*j+2], hb[4*j+3] };
            ushort4 tl = { lb[4*j], lb[4*j+1], lb[4*j+2], lb[4*j+3] };
            *(ushort4*)&dh[4*j] = th;
            *(ushort4*)&dl[4*j] = tl;
        }
    } else {
        ushort_t* dh = wTo + (size_t)n * DIM + k0;
#pragma unroll
        for (int j = 0; j < 8; j++) {
            ushort4 th = { hb[4*j], hb[4*j+1], hb[4*j+2], hb[4*j+3] };
            *(ushort4*)&dh[4*j] = th;
        }
    }
}

// ---------------- Kernel 1: QKV projection, LDS-staged MFMA (hi/lo bf16) -----
// grid (NH, rows/64, 3), 256 thr (4 waves). 64x64 tile, BK=32, LDS dbuf.
// LDS chunk layout [rowgroup w][kchunk g][row m] -> frag read chunk == tid
// (wave-contiguous 1024B ds_read_b128). Staging: 16B/lane coalesced global
// loads issued one k-step ahead into registers, ds_write after compute.
__launch_bounds__(256, 4)
__global__ void k_gemm_qkv(const ushort_t* __restrict__ xh, const ushort_t* __restrict__ xl,
                           const ushort_t* __restrict__ wTh, const ushort_t* __restrict__ wTl,
                           const float* __restrict__ bq, const float* __restrict__ bk,
                           const float* __restrict__ bv,
                           const float* __restrict__ lbeta, const float* __restrict__ ltemp,
                           float* __restrict__ Qf2, float* __restrict__ Kf,
                           float* __restrict__ Vv2)
{
    const int z = blockIdx.z, h = blockIdx.x;
    const int rowBase = blockIdx.y * 64;
    const int colBase = h * 64;
    const float* bias = (z == 0) ? bq : (z == 1) ? bk : bv;

    // [buf][Ah,Al,Bh,Bl][256 chunks x 8 ushort]
    __shared__ __align__(16) ushort_t lds[2][4][2048];

    const int tid = threadIdx.x;
    const int l = tid & 63, wv = tid >> 6;
    const int m = l & 15, g = l >> 4;

    // staging: thread t loads 16B at (row rl, kchunk cc) of each tile
    const int rl = tid >> 2, cc = tid & 3;
    const int ci = ((rl >> 4) * 64 + cc * 16 + (rl & 15)) * 8;   // LDS ushort offset
    const ushort_t* gAh = xh + (size_t)(rowBase + rl) * DIM + cc * 8;
    const ushort_t* gAl = xl + (size_t)(rowBase + rl) * DIM + cc * 8;
    const ushort_t* gBh = wTh + (size_t)z * DIM * DIM + (size_t)(colBase + rl) * DIM + cc * 8;
    const ushort_t* gBl = wTl + (size_t)z * DIM * DIM + (size_t)(colBase + rl) * DIM + cc * 8;

    f32x4 acc[4] = { {0,0,0,0}, {0,0,0,0}, {0,0,0,0}, {0,0,0,0} };

    // prologue: stage k-step 0 into buf 0
    {
        bf16x8 a0 = *(const bf16x8*)gAh;
        bf16x8 a1 = *(const bf16x8*)gAl;
        bf16x8 b0 = *(const bf16x8*)gBh;
        bf16x8 b1 = *(const bf16x8*)gBl;
        *(bf16x8*)&lds[0][0][ci] = a0;
        *(bf16x8*)&lds[0][1][ci] = a1;
        *(bf16x8*)&lds[0][2][ci] = b0;
        *(bf16x8*)&lds[0][3][ci] = b1;
    }
    __syncthreads();

    for (int it = 0; it < 16; ++it) {
        const int cur = it & 1;
        bf16x8 nAh, nAl, nBh, nBl;
        if (it < 15) {
            const int K = (it + 1) * 32;
            nAh = *(const bf16x8*)(gAh + K);
            nAl = *(const bf16x8*)(gAl + K);
            nBh = *(const bf16x8*)(gBh + K);
            nBl = *(const bf16x8*)(gBl + K);
        }
        // fragments: A chunk == tid; B chunk == n*64 + l  (contiguous per wave)
        bf16x8 ah = *(const bf16x8*)&lds[cur][0][tid * 8];
        bf16x8 al = *(const bf16x8*)&lds[cur][1][tid * 8];
#pragma unroll
        for (int n = 0; n < 4; n++) {
            bf16x8 bh = *(const bf16x8*)&lds[cur][2][(n * 64 + l) * 8];
            bf16x8 bl = *(const bf16x8*)&lds[cur][3][(n * 64 + l) * 8];
            acc[n] = __builtin_amdgcn_mfma_f32_16x16x32_bf16(ah, bh, acc[n], 0, 0, 0);
            acc[n] = __builtin_amdgcn_mfma_f32_16x16x32_bf16(al, bh, acc[n], 0, 0, 0);
            acc[n] = __builtin_amdgcn_mfma_f32_16x16x32_bf16(ah, bl, acc[n], 0, 0, 0);
        }
        if (it < 15) {
            const int nxt = cur ^ 1;
            *(bf16x8*)&lds[nxt][0][ci] = nAh;
            *(bf16x8*)&lds[nxt][1][ci] = nAl;
            *(bf16x8*)&lds[nxt][2][ci] = nBh;
            *(bf16x8*)&lds[nxt][3][ci] = nBl;
            __syncthreads();
        }
    }

    // epilogue: C/D layout col=lane&15, row=(lane>>4)*4+reg  [m89 verified]
    if (z == 2) {
#pragma unroll
        for (int n = 0; n < 4; n++) {
            int c = n * 16 + m;
            float bval = bias[colBase + c];
#pragma unroll
            for (int r = 0; r < 4; r++) {
                int rr = rowBase + wv * 16 + g * 4 + r;
                int bb = rr >> 10, t = rr & (TT - 1);
                Vv2[(((size_t)(bb * NH + h)) * TT + t) * HD + c] = (acc[n][r] + bval) * LOG2EF;
            }
        }
    } else {
        float beta = expf(lbeta[h]);
        float itemp = 1.0f / expf(ltemp[h]);
        float oscale = (z == 0) ? (LN2F / beta) : (1.0f / beta);
        float* __restrict__ dst = (z == 0) ? Qf2 : Kf;
#pragma unroll
        for (int n = 0; n < 4; n++) {
            int c = n * 16 + m;
            float bval = bias[colBase + c];
#pragma unroll
            for (int r = 0; r < 4; r++) {
                int rr = rowBase + wv * 16 + g * 4 + r;
                int bb = rr >> 10, t = rr & (TT - 1);
                float val = (acc[n][r] + bval) * itemp;
                float zz = beta * val;
                float sp = (fmaxf(zz, 0.f) + log1pf(expf(-fabsf(zz)))) * oscale;
                dst[(((size_t)(bb * NH + h)) * TT + t) * HD + c] = sp;
            }
        }
    }
}

// ---------------- Kernel 2: per-chunk local sums ----------------
__launch_bounds__(256)
__global__ void k_chunk_reduce(const float* __restrict__ Kf, const float* __restrict__ Vv2,
                               float* __restrict__ aA, float* __restrict__ aD,
                               float* __restrict__ aCM)
{
    const int c = blockIdx.x >> 1, qh = blockIdx.x & 1;
    const int bh = blockIdx.z * NH + blockIdx.y;
    const int tid = threadIdx.x;

    __shared__ __align__(16) float sK[CL * HD];
    __shared__ __align__(16) float sV2[CL * HD];
    __shared__ __align__(16) float sM02[CL * HD];

    size_t base = ((size_t)bh * TT + (size_t)c * CL) * HD;
    const float4* K4 = (const float4*)(Kf + base);
    const float4* V4 = (const float4*)(Vv2 + base);
#pragma unroll
    for (int r = 0; r < 2; r++) {
        int f = tid + 256 * r;
        float4 kv = K4[f];
        ((float4*)sK)[f] = kv;
        float4 mm;
        mm.x = flog2(kv.x + EPSF); mm.y = flog2(kv.y + EPSF);
        mm.z = flog2(kv.z + EPSF); mm.w = flog2(kv.w + EPSF);
        ((float4*)sM02)[f] = mm;
        ((float4*)sV2)[f] = V4[f];
    }
    __syncthreads();

    const int p = tid & 63, qo = tid >> 6;
    const int q0 = qh * 32 + qo * 8;
    float A[8] = {};
    float AD = 0.f, cmx = 0.f;
    const bool doD = (qh == 0) && (tid < 64);

    for (int s = 0; s < CL; s++) {
        float vp = sV2[s * HD + p];
        float mp = sM02[s * HD + p];
        float4 ka = *(const float4*)&sK[s * HD + q0];
        float4 kb = *(const float4*)&sK[s * HD + q0 + 4];
        A[0] += fexp2(fmaf(vp, ka.x, mp));
        A[1] += fexp2(fmaf(vp, ka.y, mp));
        A[2] += fexp2(fmaf(vp, ka.z, mp));
        A[3] += fexp2(fmaf(vp, ka.w, mp));
        A[4] += fexp2(fmaf(vp, kb.x, mp));
        A[5] += fexp2(fmaf(vp, kb.y, mp));
        A[6] += fexp2(fmaf(vp, kb.z, mp));
        A[7] += fexp2(fmaf(vp, kb.w, mp));
        if (doD) {
            float kn = sK[s * HD + tid];
            float mn = sM02[s * HD + tid];
            AD += fexp2(fmaf(kn, LOG2EF, mn));
            cmx = fmaxf(cmx, kn + EPSF);
        }
    }

    size_t abase = ((size_t)bh * CH + c) * 4096 + (size_t)p * HD + q0;
    float4 o0 = { A[0], A[1], A[2], A[3] };
    float4 o1 = { A[4], A[5], A[6], A[7] };
    *(float4*)&aA[abase] = o0;
    *(float4*)&aA[abase + 4] = o1;
    if (doD) {
        size_t dbase = ((size_t)bh * CH + c) * HD + tid;
        aD[dbase] = AD; aCM[dbase] = cmx;
    }
}

// ---------------- Kernel 3: exclusive scan of chunk aggregates ----------------
__global__ void k_scan_agg(float* __restrict__ aA, float* __restrict__ aD,
                           float* __restrict__ aCM, int BH)
{
    int idx = blockIdx.x * 256 + threadIdx.x;
    int nA = BH * 4096, nD = BH * 64;
    if (idx < nA) {
        int bh = idx >> 12, pn = idx & 4095;
        float Sr = 0.f;
        for (int c = 0; c < CH; c++) {
            size_t off = ((size_t)bh * CH + c) * 4096 + pn;
            float t = aA[off]; aA[off] = Sr; Sr += t;
        }
    } else if (idx < nA + nD) {
        int i = idx - nA; int bh = i >> 6, n = i & 63;
        float Sr = 0.f;
        for (int c = 0; c < CH; c++) {
            size_t off = ((size_t)bh * CH + c) * HD + n;
            float t = aD[off]; aD[off] = Sr; Sr += t;
        }
    } else if (idx < nA + 2 * nD) {
        int i = idx - nA - nD; int bh = i >> 6, n = i & 63;
        float r = 0.f;
        for (int c = 0; c < CH; c++) {
            size_t off = ((size_t)bh * CH + c) * HD + n;
            float v = aCM[off]; aCM[off] = r; r = fmaxf(r, v);
        }
    }
}

// ---------------- Kernel 4: denominator / c1 per t ----------------
__launch_bounds__(64)
__global__ void k_den(const float* __restrict__ Kf, const float* __restrict__ Qf2,
                      const float* __restrict__ aD, const float* __restrict__ aCM,
                      float* __restrict__ c1f, float* __restrict__ invd)
{
    const int c = blockIdx.x;
    const int bh = blockIdx.z * NH + blockIdx.y;
    const int n = threadIdx.x;
    size_t dbase = ((size_t)bh * CH + c) * HD + n;
    float AD = aD[dbase], cmx = aCM[dbase];
    size_t base = ((size_t)bh * TT + (size_t)c * CL) * HD + n;
    float* outc = c1f + (size_t)bh * TT + c * CL;
    float* outi = invd + (size_t)bh * TT + c * CL;

    for (int s = 0; s < CL; s++) {
        float kn = Kf[base + (size_t)s * HD];
        float qn = Qf2[base + (size_t)s * HD];
        float mn = flog2(kn + EPSF);
        AD += fexp2(fmaf(kn, LOG2EF, mn));
        cmx = fmaxf(cmx, kn + EPSF);
        float t1 = qn * flog2(cmx);
        float t2 = qn * flog2(AD);
#pragma unroll
        for (int off = 1; off <= 32; off <<= 1) {
            t1 += __shfl_xor(t1, off);
            t2 += __shfl_xor(t2, off);
        }
        if (n == 0) {
            outc[s] = t1;
            outi[s] = 1.0f / (t2 - t1 + EPSF);
        }
    }
}

// ---------------- Kernel 5: within-chunk rescan + output Y (bf16) -------------
__launch_bounds__(256)
__global__ void k_chunk_out(const float* __restrict__ Kf, const float* __restrict__ Vv2,
                            const float* __restrict__ Qf2, const float* __restrict__ aA,
                            const float* __restrict__ c1f, const float* __restrict__ invd,
                            const float* __restrict__ lsharp, ushort_t* __restrict__ Ymb)
{
    const int c = blockIdx.x, hh = blockIdx.y, bb = blockIdx.z;
    const int bh = bb * NH + hh;
    const int tid = threadIdx.x;

    __shared__ __align__(16) float sK[CL * HD];
    __shared__ __align__(16) float sV2[CL * HD];
    __shared__ __align__(16) float sM02[CL * HD];
    __shared__ __align__(16) float sQ2[CL * HD];

    size_t base = ((size_t)bh * TT + (size_t)c * CL) * HD;
    const float4* K4 = (const float4*)(Kf + base);
    const float4* V4 = (const float4*)(Vv2 + base);
    const float4* Q4 = (const float4*)(Qf2 + base);
#pragma unroll
    for (int r = 0; r < 2; r++) {
        int f = tid + 256 * r;
        float4 kv = K4[f];
        ((float4*)sK)[f] = kv;
        float4 mm;
        mm.x = flog2(kv.x + EPSF); mm.y = flog2(kv.y + EPSF);
        mm.z = flog2(kv.z + EPSF); mm.w = flog2(kv.w + EPSF);
        ((float4*)sM02)[f] = mm;
        ((float4*)sV2)[f] = V4[f];
        ((float4*)sQ2)[f] = Q4[f];
    }
    __syncthreads();

    const int lane = tid & 63, w = tid >> 6;
    const int g = lane >> 3, qil = lane & 7;
    const int qA = w * 8 + qil, qB = qA + 32;
    const int p0 = g * 8;

    float A[8], Bq[8];
    size_t abase = ((size_t)bh * CH + c) * 4096;
#pragma unroll
    for (int j = 0; j < 8; j++) {
        A[j]  = aA[abase + (size_t)(p0 + j) * HD + qA];
        Bq[j] = aA[abase + (size_t)(p0 + j) * HD + qB];
    }
    const float sharp = expf(lsharp[hh]);
    const float invT = 1.0f / (float)TT;
    const float* c1p = c1f + (size_t)bh * TT + c * CL;
    const float* ivp = invd + (size_t)bh * TT + c * CL;

    for (int s = 0; s < CL; s++) {
        float kqA = sK[s * HD + qA];
        float kqB = sK[s * HD + qB];
        float partA = 0.f, partB = 0.f;
#pragma unroll
        for (int j4 = 0; j4 < 2; j4++) {
            float4 vv = *(const float4*)&sV2[s * HD + p0 + j4 * 4];
            float4 mm = *(const float4*)&sM02[s * HD + p0 + j4 * 4];
            float4 qv = *(const float4*)&sQ2[s * HD + p0 + j4 * 4];
#define STEP(comp, jj) { \
            A[jj]  += fexp2(fmaf(vv.comp, kqA, mm.comp)); \
            partA = fmaf(qv.comp, flog2(A[jj]), partA); \
            Bq[jj] += fexp2(fmaf(vv.comp, kqB, mm.comp)); \
            partB = fmaf(qv.comp, flog2(Bq[jj]), partB); }
            STEP(x, j4 * 4 + 0)
            STEP(y, j4 * 4 + 1)
            STEP(z, j4 * 4 + 2)
            STEP(w, j4 * 4 + 3)
#undef STEP
        }
        partA += __shfl_xor(partA, 8);
        partA += __shfl_xor(partA, 16);
        partA += __shfl_xor(partA, 32);
        partB += __shfl_xor(partB, 8);
        partB += __shfl_xor(partB, 16);
        partB += __shfl_xor(partB, 32);

        float c1v = c1p[s], iv = ivp[s];
        int tg = c * CL + s;
        float scale = (float)(tg + 1) * invT;
        float yA = (partA - c1v) * iv;
        float yB = (partB - c1v) * iv;
        float oA = copysignf(fexp2(sharp * flog2(fabsf(yA))), yA) * scale;
        float oB = copysignf(fexp2(sharp * flog2(fabsf(yB))), yB) * scale;
        if (g == 0) {
            ushort_t* yrow = Ymb + ((size_t)(bb * TT + tg)) * DIM + hh * HD;
            yrow[qA] = f2bf(oA);
            yrow[qB] = f2bf(oB);
        }
    }
}

// ---------------- Kernel 6: output projection, LDS-staged MFMA (bf16) ---------
// 32x64 tile, 256 thr (4 waves: 2 rowgroups x 2 colgroups), grid (8,64)=512.
__launch_bounds__(256, 4)
__global__ void k_gemm_out(const ushort_t* __restrict__ Ymb, const ushort_t* __restrict__ wTo,
                           const float* __restrict__ bias, float* __restrict__ out)
{
    const int colBase = blockIdx.x * 64;
    const int rowBase = blockIdx.y * 32;

    __shared__ __align__(16) ushort_t sA[2][1024];   // 32 rows x 32 k  (128 chunks)
    __shared__ __align__(16) ushort_t sB[2][2048];   // 64 cols x 32 k  (256 chunks)

    const int tid = threadIdx.x;
    const int l = tid & 63, wv = tid >> 6;
    const int m = l & 15, g = l >> 4;
    const int wr = wv & 1, wc = wv >> 1;

    // B staging: all 256 threads (64 cols x 4 chunks)
    const int rlB = tid >> 2, ccB = tid & 3;
    const int ciB = ((rlB >> 4) * 64 + ccB * 16 + (rlB & 15)) * 8;
    const ushort_t* gB = wTo + (size_t)(colBase + rlB) * DIM + ccB * 8;
    // A staging: threads 0..127 (32 rows x 4 chunks)
    const int rlA = (tid & 127) >> 2, ccA = tid & 3;
    const int ciA = ((rlA >> 4) * 64 + ccA * 16 + (rlA & 15)) * 8;
    const ushort_t* gA = Ymb + (size_t)(rowBase + rlA) * DIM + ccA * 8;
    const bool doA = tid < 128;

    f32x4 acc[2] = { {0,0,0,0}, {0,0,0,0} };

    {
        bf16x8 b0 = *(const bf16x8*)gB;
        *(bf16x8*)&sB[0][ciB] = b0;
        if (doA) {
            bf16x8 a0 = *(const bf16x8*)gA;
            *(bf16x8*)&sA[0][ciA] = a0;
        }
    }
    __syncthreads();

    for (int it = 0; it < 16; ++it) {
        const int cur = it & 1;
        bf16x8 nA, nB;
        if (it < 15) {
            const int K = (it + 1) * 32;
            nB = *(const bf16x8*)(gB + K);
            if (doA) nA = *(const bf16x8*)(gA + K);
        }
        bf16x8 a = *(const bf16x8*)&sA[cur][(wr * 64 + l) * 8];
#pragma unroll
        for (int n = 0; n < 2; n++) {
            bf16x8 b = *(const bf16x8*)&sB[cur][((wc * 2 + n) * 64 + l) * 8];
            acc[n] = __builtin_amdgcn_mfma_f32_16x16x32_bf16(a, b, acc[n], 0, 0, 0);
        }
        if (it < 15) {
            const int nxt = cur ^ 1;
            *(bf16x8*)&sB[nxt][ciB] = nB;
            if (doA) *(bf16x8*)&sA[nxt][ciA] = nA;
            __syncthreads();
        }
    }

#pragma unroll
    for (int n = 0; n < 2; n++) {
        int c = colBase + wc * 32 + n * 16 + m;
        float bval = bias[c];
#pragma unroll
        for (int r = 0; r < 4; r++) {
            int rr = rowBase + wr * 16 + g * 4 + r;
            out[(size_t)rr * DIM + c] = acc[n][r] + bval;
        }
    }
}

extern "C" void kernel_launch(void* const* d_in, const int* in_sizes, int n_in,
                              void* d_out, int out_size, void* d_ws, size_t ws_size,
                              hipStream_t stream)
{
    const float* x  = (const float*)d_in[0];
    const float* wq = (const float*)d_in[1];
    const float* bq = (const float*)d_in[2];
    const float* wk = (const float*)d_in[3];
    const float* bk = (const float*)d_in[4];
    const float* wv = (const float*)d_in[5];
    const float* bv = (const float*)d_in[6];
    const float* wo = (const float*)d_in[7];
    const float* bo = (const float*)d_in[8];
    const float* lb = (const float*)d_in[9];
    const float* lt = (const float*)d_in[10];
    const float* ls = (const float*)d_in[11];

    const int B  = in_sizes[0] / (TT * DIM);   // 2
    const int BH = B * NH;                     // 16

    float* ws = (float*)d_ws;
    const size_t nQ = (size_t)BH * TT * HD;      // 1,048,576 floats
    float* Qf2 = ws;
    float* Kf  = Qf2 + nQ;
    float* Vv2 = Kf + nQ;
    float* region = Vv2 + nQ;                    // phase-aliased region

    // phase 1-2 (cvt + qkv): bf16 staging lives in region
    ushort_t* xh  = (ushort_t*)region;                                  // B*TT*DIM bf16
    ushort_t* xl  = xh + (size_t)B * TT * DIM;
    ushort_t* wTh = (ushort_t*)(region + (size_t)B * TT * DIM);         // 3*DIM*DIM bf16
    ushort_t* wTl = wTh + (size_t)3 * DIM * DIM;
    // phase 3+ : scan state overwrites the staging area
    ushort_t* Ymb = (ushort_t*)region;                                  // B*TT*DIM bf16
    float* aA  = region + (size_t)B * TT * DIM;                         // BH*CH*4096
    float* aD  = aA  + (size_t)BH * CH * 4096;
    float* aCM = aD  + (size_t)BH * CH * HD;
    float* c1f = aCM + (size_t)BH * CH * HD;
    float* invd= c1f + (size_t)BH * TT;
    ushort_t* wTo = (ushort_t*)(invd + (size_t)BH * TT);                // persists to end

    k_cvt_x<<<(B * TT * DIM) / 1024, 256, 0, stream>>>(x, xh, xl);

    dim3 gw(DIM / 64, DIM / 128, 4);
    k_cvt_w<<<gw, 256, 0, stream>>>(wq, wk, wv, wo, wTh, wTl, wTo);

    dim3 g1(NH, (B * TT) / 64, 3);
    k_gemm_qkv<<<g1, 256, 0, stream>>>(xh, xl, wTh, wTl, bq, bk, bv, lb, lt, Qf2, Kf, Vv2);

    dim3 g2(CH * 2, NH, B);
    k_chunk_reduce<<<g2, 256, 0, stream>>>(Kf, Vv2, aA, aD, aCM);

    int ntot = BH * 4096 + 2 * BH * 64;
    k_scan_agg<<<(ntot + 255) / 256, 256, 0, stream>>>(aA, aD, aCM, BH);

    dim3 g4(CH, NH, B);
    k_den<<<g4, 64, 0, stream>>>(Kf, Qf2, aD, aCM, c1f, invd);

    k_chunk_out<<<g4, 256, 0, stream>>>(Kf, Vv2, Qf2, aA, c1f, invd, ls, Ymb);

    dim3 g6(DIM / 64, (B * TT) / 32);
    k_gemm_out<<<g6, 256, 0, stream>>>(Ymb, wTo, bo, (float*)d_out);
}

// Round 10
// 98.626 us; speedup vs baseline: 1.5049x; 1.0725x over previous
//
#include <hip/hip_runtime.h>
#include <hip/hip_bf16.h>
#include <math.h>

#define DIM 512
#define NH 8
#define HD 64
#define TT 1024
#define CH 64      // chunks per (b,h) sequence
#define CL 16      // chunk length (CH*CL == TT)
#define EPSF 1e-5f
#define LN2F 0.69314718056f
#define LOG2EF 1.44269504089f

typedef unsigned short ushort_t;
typedef __attribute__((ext_vector_type(8))) short bf16x8;
typedef __attribute__((ext_vector_type(4))) float f32x4;

// raw gfx950 hardware transcendentals: v_exp_f32 = 2^x, v_log_f32 = log2(x)
__device__ __forceinline__ float fexp2(float x) { return __builtin_amdgcn_exp2f(x); }
__device__ __forceinline__ float flog2(float x) { return __builtin_amdgcn_logf(x); }

__device__ __forceinline__ ushort_t f2bf(float f) {
    union { float f; unsigned u; } v; v.f = f;
    unsigned r = v.u + 0x7FFFu + ((v.u >> 16) & 1u);
    return (ushort_t)(r >> 16);
}
__device__ __forceinline__ float bf2f(ushort_t h) {
    union { unsigned u; float f; } v; v.u = ((unsigned)h) << 16;
    return v.f;
}

// ---------------- cvt: x -> bf16 hi/lo ----------------
__launch_bounds__(256)
__global__ void k_cvt_x(const float* __restrict__ x, ushort_t* __restrict__ xh,
                        ushort_t* __restrict__ xl)
{
    int i = (blockIdx.x * 256 + threadIdx.x) * 4;
    float4 v = *(const float4*)&x[i];
    ushort4 h, l;
    h.x = f2bf(v.x); l.x = f2bf(v.x - bf2f(h.x));
    h.y = f2bf(v.y); l.y = f2bf(v.y - bf2f(h.y));
    h.z = f2bf(v.z); l.z = f2bf(v.z - bf2f(h.z));
    h.w = f2bf(v.w); l.w = f2bf(v.w - bf2f(h.w));
    *(ushort4*)&xh[i] = h;
    *(ushort4*)&xl[i] = l;
}

// ---------------- cvt: weights -> transposed bf16 [n][k] ----------------
__launch_bounds__(256)
__global__ void k_cvt_w(const float* __restrict__ wq, const float* __restrict__ wk,
                        const float* __restrict__ wv, const float* __restrict__ wo,
                        ushort_t* __restrict__ wTh, ushort_t* __restrict__ wTl,
                        ushort_t* __restrict__ wTo)
{
    const int mat = blockIdx.z;
    const float* w = (mat == 0) ? wq : (mat == 1) ? wk : (mat == 2) ? wv : wo;
    const int n  = blockIdx.x * 64 + (threadIdx.x & 63);
    const int k0 = blockIdx.y * 128 + (threadIdx.x >> 6) * 32;

    ushort_t hb[32], lb[32];
#pragma unroll
    for (int j = 0; j < 32; j++) {
        float v = w[(size_t)(k0 + j) * DIM + n];
        hb[j] = f2bf(v);
        lb[j] = f2bf(v - bf2f(hb[j]));
    }
    if (mat < 3) {
        ushort_t* dh = wTh + (size_t)mat * DIM * DIM + (size_t)n * DIM + k0;
        ushort_t* dl = wTl + (size_t)mat * DIM * DIM + (size_t)n * DIM + k0;
#pragma unroll
        for (int j = 0; j < 8; j++) {
            ushort4 th = { hb[4*j], hb[4*j+1], hb[4*j+2], hb[4*j+3] };
            ushort4 tl = { lb[4*j], lb[4*j+1], lb[4*j+2], lb[4*j+3] };
            *(ushort4*)&dh[4*j] = th;
            *(ushort4*)&dl[4*j] = tl;
        }
    } else {
        ushort_t* dh = wTo + (size_t)n * DIM + k0;
#pragma unroll
        for (int j = 0; j < 8; j++) {
            ushort4 th = { hb[4*j], hb[4*j+1], hb[4*j+2], hb[4*j+3] };
            *(ushort4*)&dh[4*j] = th;
        }
    }
}

// ---------------- Kernel 1: QKV projection, LDS-staged MFMA (hi/lo bf16) -----
__launch_bounds__(256, 4)
__global__ void k_gemm_qkv(const ushort_t* __restrict__ xh, const ushort_t* __restrict__ xl,
                           const ushort_t* __restrict__ wTh, const ushort_t* __restrict__ wTl,
                           const float* __restrict__ bq, const float* __restrict__ bk,
                           const float* __restrict__ bv,
                           const float* __restrict__ lbeta, const float* __restrict__ ltemp,
                           float* __restrict__ Qf2, float* __restrict__ Kf,
                           float* __restrict__ Vv2)
{
    const int z = blockIdx.z, h = blockIdx.x;
    const int rowBase = blockIdx.y * 64;
    const int colBase = h * 64;
    const float* bias = (z == 0) ? bq : (z == 1) ? bk : bv;

    __shared__ __align__(16) ushort_t lds[2][4][2048];

    const int tid = threadIdx.x;
    const int l = tid & 63, wv = tid >> 6;
    const int m = l & 15, g = l >> 4;

    const int rl = tid >> 2, cc = tid & 3;
    const int ci = ((rl >> 4) * 64 + cc * 16 + (rl & 15)) * 8;
    const ushort_t* gAh = xh + (size_t)(rowBase + rl) * DIM + cc * 8;
    const ushort_t* gAl = xl + (size_t)(rowBase + rl) * DIM + cc * 8;
    const ushort_t* gBh = wTh + (size_t)z * DIM * DIM + (size_t)(colBase + rl) * DIM + cc * 8;
    const ushort_t* gBl = wTl + (size_t)z * DIM * DIM + (size_t)(colBase + rl) * DIM + cc * 8;

    f32x4 acc[4] = { {0,0,0,0}, {0,0,0,0}, {0,0,0,0}, {0,0,0,0} };

    {
        bf16x8 a0 = *(const bf16x8*)gAh;
        bf16x8 a1 = *(const bf16x8*)gAl;
        bf16x8 b0 = *(const bf16x8*)gBh;
        bf16x8 b1 = *(const bf16x8*)gBl;
        *(bf16x8*)&lds[0][0][ci] = a0;
        *(bf16x8*)&lds[0][1][ci] = a1;
        *(bf16x8*)&lds[0][2][ci] = b0;
        *(bf16x8*)&lds[0][3][ci] = b1;
    }
    __syncthreads();

    for (int it = 0; it < 16; ++it) {
        const int cur = it & 1;
        bf16x8 nAh, nAl, nBh, nBl;
        if (it < 15) {
            const int K = (it + 1) * 32;
            nAh = *(const bf16x8*)(gAh + K);
            nAl = *(const bf16x8*)(gAl + K);
            nBh = *(const bf16x8*)(gBh + K);
            nBl = *(const bf16x8*)(gBl + K);
        }
        bf16x8 ah = *(const bf16x8*)&lds[cur][0][tid * 8];
        bf16x8 al = *(const bf16x8*)&lds[cur][1][tid * 8];
#pragma unroll
        for (int n = 0; n < 4; n++) {
            bf16x8 bh = *(const bf16x8*)&lds[cur][2][(n * 64 + l) * 8];
            bf16x8 bl = *(const bf16x8*)&lds[cur][3][(n * 64 + l) * 8];
            acc[n] = __builtin_amdgcn_mfma_f32_16x16x32_bf16(ah, bh, acc[n], 0, 0, 0);
            acc[n] = __builtin_amdgcn_mfma_f32_16x16x32_bf16(al, bh, acc[n], 0, 0, 0);
            acc[n] = __builtin_amdgcn_mfma_f32_16x16x32_bf16(ah, bl, acc[n], 0, 0, 0);
        }
        if (it < 15) {
            const int nxt = cur ^ 1;
            *(bf16x8*)&lds[nxt][0][ci] = nAh;
            *(bf16x8*)&lds[nxt][1][ci] = nAl;
            *(bf16x8*)&lds[nxt][2][ci] = nBh;
            *(bf16x8*)&lds[nxt][3][ci] = nBl;
            __syncthreads();
        }
    }

    if (z == 2) {
#pragma unroll
        for (int n = 0; n < 4; n++) {
            int c = n * 16 + m;
            float bval = bias[colBase + c];
#pragma unroll
            for (int r = 0; r < 4; r++) {
                int rr = rowBase + wv * 16 + g * 4 + r;
                int bb = rr >> 10, t = rr & (TT - 1);
                Vv2[(((size_t)(bb * NH + h)) * TT + t) * HD + c] = (acc[n][r] + bval) * LOG2EF;
            }
        }
    } else {
        float beta = expf(lbeta[h]);
        float itemp = 1.0f / expf(ltemp[h]);
        float oscale = (z == 0) ? (LN2F / beta) : (1.0f / beta);
        float* __restrict__ dst = (z == 0) ? Qf2 : Kf;
#pragma unroll
        for (int n = 0; n < 4; n++) {
            int c = n * 16 + m;
            float bval = bias[colBase + c];
#pragma unroll
            for (int r = 0; r < 4; r++) {
                int rr = rowBase + wv * 16 + g * 4 + r;
                int bb = rr >> 10, t = rr & (TT - 1);
                float val = (acc[n][r] + bval) * itemp;
                float zz = beta * val;
                float sp = (fmaxf(zz, 0.f) + log1pf(expf(-fabsf(zz)))) * oscale;
                dst[(((size_t)(bb * NH + h)) * TT + t) * HD + c] = sp;
            }
        }
    }
}

// ---------------- Kernel 2: per-chunk local sums (CL=16) ----------------
// grid (CH*2, NH, B) = 2048 blocks -> 8 blocks/CU.
__launch_bounds__(256)
__global__ void k_chunk_reduce(const float* __restrict__ Kf, const float* __restrict__ Vv2,
                               float* __restrict__ aA, float* __restrict__ aD,
                               float* __restrict__ aCM)
{
    const int c = blockIdx.x >> 1, qh = blockIdx.x & 1;
    const int bh = blockIdx.z * NH + blockIdx.y;
    const int tid = threadIdx.x;

    __shared__ __align__(16) float sK[CL * HD];
    __shared__ __align__(16) float sV2[CL * HD];
    __shared__ __align__(16) float sM02[CL * HD];

    size_t base = ((size_t)bh * TT + (size_t)c * CL) * HD;
    const float4* K4 = (const float4*)(Kf + base);
    const float4* V4 = (const float4*)(Vv2 + base);
    {
        int f = tid;                       // 256 float4 slots == 256 threads
        float4 kv = K4[f];
        ((float4*)sK)[f] = kv;
        float4 mm;
        mm.x = flog2(kv.x + EPSF); mm.y = flog2(kv.y + EPSF);
        mm.z = flog2(kv.z + EPSF); mm.w = flog2(kv.w + EPSF);
        ((float4*)sM02)[f] = mm;
        ((float4*)sV2)[f] = V4[f];
    }
    __syncthreads();

    const int p = tid & 63, qo = tid >> 6;
    const int q0 = qh * 32 + qo * 8;
    float A[8] = {};
    float AD = 0.f, cmx = 0.f;
    const bool doD = (qh == 0) && (tid < 64);

    for (int s = 0; s < CL; s++) {
        float vp = sV2[s * HD + p];
        float mp = sM02[s * HD + p];
        float4 ka = *(const float4*)&sK[s * HD + q0];
        float4 kb = *(const float4*)&sK[s * HD + q0 + 4];
        A[0] += fexp2(fmaf(vp, ka.x, mp));
        A[1] += fexp2(fmaf(vp, ka.y, mp));
        A[2] += fexp2(fmaf(vp, ka.z, mp));
        A[3] += fexp2(fmaf(vp, ka.w, mp));
        A[4] += fexp2(fmaf(vp, kb.x, mp));
        A[5] += fexp2(fmaf(vp, kb.y, mp));
        A[6] += fexp2(fmaf(vp, kb.z, mp));
        A[7] += fexp2(fmaf(vp, kb.w, mp));
        if (doD) {
            float kn = sK[s * HD + tid];
            float mn = sM02[s * HD + tid];
            AD += fexp2(fmaf(kn, LOG2EF, mn));
            cmx = fmaxf(cmx, kn + EPSF);
        }
    }

    size_t abase = ((size_t)bh * CH + c) * 4096 + (size_t)p * HD + q0;
    float4 o0 = { A[0], A[1], A[2], A[3] };
    float4 o1 = { A[4], A[5], A[6], A[7] };
    *(float4*)&aA[abase] = o0;
    *(float4*)&aA[abase + 4] = o1;
    if (doD) {
        size_t dbase = ((size_t)bh * CH + c) * HD + tid;
        aD[dbase] = AD; aCM[dbase] = cmx;
    }
}

// ---------------- Kernel 3: exclusive scan of chunk aggregates (float4) -------
__global__ void k_scan_agg(float* __restrict__ aA, float* __restrict__ aD,
                           float* __restrict__ aCM, int BH)
{
    int idx = blockIdx.x * 256 + threadIdx.x;
    int nA4 = BH * 1024;          // BH*4096/4
    int nD4 = BH * 16;            // BH*64/4
    if (idx < nA4) {
        int bh = idx >> 10, pn4 = (idx & 1023) * 4;
        float4 Sr = {0.f, 0.f, 0.f, 0.f};
        for (int c = 0; c < CH; c++) {
            float* p = &aA[((size_t)bh * CH + c) * 4096 + pn4];
            float4 t = *(float4*)p;
            *(float4*)p = Sr;
            Sr.x += t.x; Sr.y += t.y; Sr.z += t.z; Sr.w += t.w;
        }
    } else if (idx < nA4 + nD4) {
        int i = idx - nA4; int bh = i >> 4, n4 = (i & 15) * 4;
        float4 Sr = {0.f, 0.f, 0.f, 0.f};
        for (int c = 0; c < CH; c++) {
            float* p = &aD[((size_t)bh * CH + c) * HD + n4];
            float4 t = *(float4*)p;
            *(float4*)p = Sr;
            Sr.x += t.x; Sr.y += t.y; Sr.z += t.z; Sr.w += t.w;
        }
    } else if (idx < nA4 + 2 * nD4) {
        int i = idx - nA4 - nD4; int bh = i >> 4, n4 = (i & 15) * 4;
        float4 r = {0.f, 0.f, 0.f, 0.f};
        for (int c = 0; c < CH; c++) {
            float* p = &aCM[((size_t)bh * CH + c) * HD + n4];
            float4 t = *(float4*)p;
            *(float4*)p = r;
            r.x = fmaxf(r.x, t.x); r.y = fmaxf(r.y, t.y);
            r.z = fmaxf(r.z, t.z); r.w = fmaxf(r.w, t.w);
        }
    }
}

// ---------------- Kernel 4: denominator / c1 per t ----------------
__launch_bounds__(64)
__global__ void k_den(const float* __restrict__ Kf, const float* __restrict__ Qf2,
                      const float* __restrict__ aD, const float* __restrict__ aCM,
                      float* __restrict__ c1f, float* __restrict__ invd)
{
    const int c = blockIdx.x;
    const int bh = blockIdx.z * NH + blockIdx.y;
    const int n = threadIdx.x;
    size_t dbase = ((size_t)bh * CH + c) * HD + n;
    float AD = aD[dbase], cmx = aCM[dbase];
    size_t base = ((size_t)bh * TT + (size_t)c * CL) * HD + n;
    float* outc = c1f + (size_t)bh * TT + c * CL;
    float* outi = invd + (size_t)bh * TT + c * CL;

    for (int s = 0; s < CL; s++) {
        float kn = Kf[base + (size_t)s * HD];
        float qn = Qf2[base + (size_t)s * HD];
        float mn = flog2(kn + EPSF);
        AD += fexp2(fmaf(kn, LOG2EF, mn));
        cmx = fmaxf(cmx, kn + EPSF);
        float t1 = qn * flog2(cmx);
        float t2 = qn * flog2(AD);
#pragma unroll
        for (int off = 1; off <= 32; off <<= 1) {
            t1 += __shfl_xor(t1, off);
            t2 += __shfl_xor(t2, off);
        }
        if (n == 0) {
            outc[s] = t1;
            outi[s] = 1.0f / (t2 - t1 + EPSF);
        }
    }
}

// ---------------- Kernel 5: within-chunk rescan + output Y (bf16, CL=16) ------
// grid (CH, NH, B) = 1024 blocks -> 4 blocks/CU = 4 waves/SIMD.
__launch_bounds__(256)
__global__ void k_chunk_out(const float* __restrict__ Kf, const float* __restrict__ Vv2,
                            const float* __restrict__ Qf2, const float* __restrict__ aA,
                            const float* __restrict__ c1f, const float* __restrict__ invd,
                            const float* __restrict__ lsharp, ushort_t* __restrict__ Ymb)
{
    const int c = blockIdx.x, hh = blockIdx.y, bb = blockIdx.z;
    const int bh = bb * NH + hh;
    const int tid = threadIdx.x;

    __shared__ __align__(16) float sK[CL * HD];
    __shared__ __align__(16) float sV2[CL * HD];
    __shared__ __align__(16) float sM02[CL * HD];
    __shared__ __align__(16) float sQ2[CL * HD];

    size_t base = ((size_t)bh * TT + (size_t)c * CL) * HD;
    const float4* K4 = (const float4*)(Kf + base);
    const float4* V4 = (const float4*)(Vv2 + base);
    const float4* Q4 = (const float4*)(Qf2 + base);
    {
        int f = tid;
        float4 kv = K4[f];
        ((float4*)sK)[f] = kv;
        float4 mm;
        mm.x = flog2(kv.x + EPSF); mm.y = flog2(kv.y + EPSF);
        mm.z = flog2(kv.z + EPSF); mm.w = flog2(kv.w + EPSF);
        ((float4*)sM02)[f] = mm;
        ((float4*)sV2)[f] = V4[f];
        ((float4*)sQ2)[f] = Q4[f];
    }
    __syncthreads();

    const int lane = tid & 63, w = tid >> 6;
    const int g = lane >> 3, qil = lane & 7;
    const int qA = w * 8 + qil, qB = qA + 32;
    const int p0 = g * 8;

    float A[8], Bq[8];
    size_t abase = ((size_t)bh * CH + c) * 4096;
#pragma unroll
    for (int j = 0; j < 8; j++) {
        A[j]  = aA[abase + (size_t)(p0 + j) * HD + qA];
        Bq[j] = aA[abase + (size_t)(p0 + j) * HD + qB];
    }
    const float sharp = expf(lsharp[hh]);
    const float invT = 1.0f / (float)TT;
    const float* c1p = c1f + (size_t)bh * TT + c * CL;
    const float* ivp = invd + (size_t)bh * TT + c * CL;

    for (int s = 0; s < CL; s++) {
        float kqA = sK[s * HD + qA];
        float kqB = sK[s * HD + qB];
        // two accumulators per q to break the serial fmaf chain
        float pA0 = 0.f, pA1 = 0.f, pB0 = 0.f, pB1 = 0.f;
#pragma unroll
        for (int j4 = 0; j4 < 2; j4++) {
            float4 vv = *(const float4*)&sV2[s * HD + p0 + j4 * 4];
            float4 mm = *(const float4*)&sM02[s * HD + p0 + j4 * 4];
            float4 qv = *(const float4*)&sQ2[s * HD + p0 + j4 * 4];
#define STEP(comp, jj, PA, PB) { \
            A[jj]  += fexp2(fmaf(vv.comp, kqA, mm.comp)); \
            PA = fmaf(qv.comp, flog2(A[jj]), PA); \
            Bq[jj] += fexp2(fmaf(vv.comp, kqB, mm.comp)); \
            PB = fmaf(qv.comp, flog2(Bq[jj]), PB); }
            STEP(x, j4 * 4 + 0, pA0, pB0)
            STEP(y, j4 * 4 + 1, pA1, pB1)
            STEP(z, j4 * 4 + 2, pA0, pB0)
            STEP(w, j4 * 4 + 3, pA1, pB1)
#undef STEP
        }
        float partA = pA0 + pA1;
        float partB = pB0 + pB1;
        partA += __shfl_xor(partA, 8);
        partA += __shfl_xor(partA, 16);
        partA += __shfl_xor(partA, 32);
        partB += __shfl_xor(partB, 8);
        partB += __shfl_xor(partB, 16);
        partB += __shfl_xor(partB, 32);

        float c1v = c1p[s], iv = ivp[s];
        int tg = c * CL + s;
        float scale = (float)(tg + 1) * invT;
        float yA = (partA - c1v) * iv;
        float yB = (partB - c1v) * iv;
        float oA = copysignf(fexp2(sharp * flog2(fabsf(yA))), yA) * scale;
        float oB = copysignf(fexp2(sharp * flog2(fabsf(yB))), yB) * scale;
        if (g == 0) {
            ushort_t* yrow = Ymb + ((size_t)(bb * TT + tg)) * DIM + hh * HD;
            yrow[qA] = f2bf(oA);
            yrow[qB] = f2bf(oB);
        }
    }
}

// ---------------- Kernel 6: output projection, LDS-staged MFMA (bf16) ---------
__launch_bounds__(256, 4)
__global__ void k_gemm_out(const ushort_t* __restrict__ Ymb, const ushort_t* __restrict__ wTo,
                           const float* __restrict__ bias, float* __restrict__ out)
{
    const int colBase = blockIdx.x * 64;
    const int rowBase = blockIdx.y * 32;

    __shared__ __align__(16) ushort_t sA[2][1024];
    __shared__ __align__(16) ushort_t sB[2][2048];

    const int tid = threadIdx.x;
    const int l = tid & 63, wv = tid >> 6;
    const int m = l & 15, g = l >> 4;
    const int wr = wv & 1, wc = wv >> 1;

    const int rlB = tid >> 2, ccB = tid & 3;
    const int ciB = ((rlB >> 4) * 64 + ccB * 16 + (rlB & 15)) * 8;
    const ushort_t* gB = wTo + (size_t)(colBase + rlB) * DIM + ccB * 8;
    const int rlA = (tid & 127) >> 2, ccA = tid & 3;
    const int ciA = ((rlA >> 4) * 64 + ccA * 16 + (rlA & 15)) * 8;
    const ushort_t* gA = Ymb + (size_t)(rowBase + rlA) * DIM + ccA * 8;
    const bool doA = tid < 128;

    f32x4 acc[2] = { {0,0,0,0}, {0,0,0,0} };

    {
        bf16x8 b0 = *(const bf16x8*)gB;
        *(bf16x8*)&sB[0][ciB] = b0;
        if (doA) {
            bf16x8 a0 = *(const bf16x8*)gA;
            *(bf16x8*)&sA[0][ciA] = a0;
        }
    }
    __syncthreads();

    for (int it = 0; it < 16; ++it) {
        const int cur = it & 1;
        bf16x8 nA, nB;
        if (it < 15) {
            const int K = (it + 1) * 32;
            nB = *(const bf16x8*)(gB + K);
            if (doA) nA = *(const bf16x8*)(gA + K);
        }
        bf16x8 a = *(const bf16x8*)&sA[cur][(wr * 64 + l) * 8];
#pragma unroll
        for (int n = 0; n < 2; n++) {
            bf16x8 b = *(const bf16x8*)&sB[cur][((wc * 2 + n) * 64 + l) * 8];
            acc[n] = __builtin_amdgcn_mfma_f32_16x16x32_bf16(a, b, acc[n], 0, 0, 0);
        }
        if (it < 15) {
            const int nxt = cur ^ 1;
            *(bf16x8*)&sB[nxt][ciB] = nB;
            if (doA) *(bf16x8*)&sA[nxt][ciA] = nA;
            __syncthreads();
        }
    }

#pragma unroll
    for (int n = 0; n < 2; n++) {
        int c = colBase + wc * 32 + n * 16 + m;
        float bval = bias[c];
#pragma unroll
        for (int r = 0; r < 4; r++) {
            int rr = rowBase + wr * 16 + g * 4 + r;
            out[(size_t)rr * DIM + c] = acc[n][r] + bval;
        }
    }
}

extern "C" void kernel_launch(void* const* d_in, const int* in_sizes, int n_in,
                              void* d_out, int out_size, void* d_ws, size_t ws_size,
                              hipStream_t stream)
{
    const float* x  = (const float*)d_in[0];
    const float* wq = (const float*)d_in[1];
    const float* bq = (const float*)d_in[2];
    const float* wk = (const float*)d_in[3];
    const float* bk = (const float*)d_in[4];
    const float* wv = (const float*)d_in[5];
    const float* bv = (const float*)d_in[6];
    const float* wo = (const float*)d_in[7];
    const float* bo = (const float*)d_in[8];
    const float* lb = (const float*)d_in[9];
    const float* lt = (const float*)d_in[10];
    const float* ls = (const float*)d_in[11];

    const int B  = in_sizes[0] / (TT * DIM);   // 2
    const int BH = B * NH;                     // 16

    float* ws = (float*)d_ws;
    const size_t nQ = (size_t)BH * TT * HD;      // 1,048,576 floats
    float* Qf2 = ws;
    float* Kf  = Qf2 + nQ;
    float* Vv2 = Kf + nQ;
    float* region = Vv2 + nQ;                    // phase-aliased region

    // phase 1-2 (cvt + qkv): bf16 staging lives in region
    ushort_t* xh  = (ushort_t*)region;                                  // B*TT*DIM bf16
    ushort_t* xl  = xh + (size_t)B * TT * DIM;
    ushort_t* wTh = (ushort_t*)(region + (size_t)B * TT * DIM);         // 3*DIM*DIM bf16
    ushort_t* wTl = wTh + (size_t)3 * DIM * DIM;
    // phase 3+ : scan state overwrites the staging area
    ushort_t* Ymb = (ushort_t*)region;                                  // B*TT*DIM bf16
    float* aA  = region + (size_t)B * TT * DIM;                         // BH*CH*4096
    float* aD  = aA  + (size_t)BH * CH * 4096;
    float* aCM = aD  + (size_t)BH * CH * HD;
    float* c1f = aCM + (size_t)BH * CH * HD;
    float* invd= c1f + (size_t)BH * TT;
    ushort_t* wTo = (ushort_t*)(invd + (size_t)BH * TT);                // persists to end

    k_cvt_x<<<(B * TT * DIM) / 1024, 256, 0, stream>>>(x, xh, xl);

    dim3 gw(DIM / 64, DIM / 128, 4);
    k_cvt_w<<<gw, 256, 0, stream>>>(wq, wk, wv, wo, wTh, wTl, wTo);

    dim3 g1(NH, (B * TT) / 64, 3);
    k_gemm_qkv<<<g1, 256, 0, stream>>>(xh, xl, wTh, wTl, bq, bk, bv, lb, lt, Qf2, Kf, Vv2);

    dim3 g2(CH * 2, NH, B);
    k_chunk_reduce<<<g2, 256, 0, stream>>>(Kf, Vv2, aA, aD, aCM);

    int ntot = BH * 1024 + 2 * BH * 16;
    k_scan_agg<<<(ntot + 255) / 256, 256, 0, stream>>>(aA, aD, aCM, BH);

    dim3 g4(CH, NH, B);
    k_den<<<g4, 64, 0, stream>>>(Kf, Qf2, aD, aCM, c1f, invd);

    k_chunk_out<<<g4, 256, 0, stream>>>(Kf, Vv2, Qf2, aA, c1f, invd, ls, Ymb);

    dim3 g6(DIM / 64, (B * TT) / 32);
    k_gemm_out<<<g6, 256, 0, stream>>>(Ymb, wTo, bo, (float*)d_out);
}